// Round 3
// baseline (716.758 us; speedup 1.0000x reference)
//
#include <hip/hip_runtime.h>
#include <hip/hip_bf16.h>
#include <stdint.h>

using bf16 = __hip_bfloat16;

constexpr int B_ = 2;
constexpr int N_ = 2304;   // 48*48 post-conv nodes

// Workspace layout (float offsets). Total 1,634,368 floats = 6.24 MB.
constexpr int OFF_WC2   = 0;        // conv w  [tap][ic][oc] (9*64*64)
constexpr int OFF_WT2   = 36864;    // tconv w [tap][ic][oc]
constexpr int OFF_W1F   = 73728;    // [64][64]
constexpr int OFF_W2F   = 77824;
constexpr int OFF_WOUTF = 81920;    // [128][64]
constexpr int OFF_A1F   = 90112;    // 128
constexpr int OFF_A2F   = 90240;
constexpr int OFF_AOUTF = 90368;
constexpr int OFF_CBF   = 90496;    // 64
constexpr int OFF_TBF   = 90560;    // 64
constexpr int OFF_FLAG  = 90624;    // 1: inputs are fp32; 0: bf16
constexpr int OFF_SQ    = 90688;    // [B*N]
constexpr int OFF_S11   = 95296;    // six [B*N] arrays
constexpr int OFF_S12   = 99904;
constexpr int OFF_S21   = 104512;
constexpr int OFF_S22   = 109120;
constexpr int OFF_S1O   = 113728;
constexpr int OFF_S2O   = 118336;
constexpr int OFF_KNN   = 122944;   // int [B*N][8] (7 used)
constexpr int OFF_BUF0  = 159808;   // 294912 floats
constexpr int OFF_BUF1  = 454720;   // also XF32 start (1,179,648 floats)
constexpr int OFF_BUF2  = 749632;
constexpr int OFF_BUF3  = 1044544;
constexpr int OFF_XF32  = OFF_BUF1; // x as fp32, dead after k1_conv

__device__ __forceinline__ float bf2f_raw(unsigned short u) {
    return __uint_as_float(((unsigned int)u) << 16);
}

// ---------------------------------------------------------------------------
// KD: dtype probe. Reads conv_w reinterpreted as bf16 (in-bounds either way).
// True bf16 weights: max|w| ~ 0.3.  fp32 misread: max >> 1e4 w.p. ~1.
// ---------------------------------------------------------------------------
__global__ __launch_bounds__(256) void kd_detect(const void* __restrict__ conv_w,
                                                 float* __restrict__ ws)
{
    __shared__ float red[256];
    const unsigned short* cw = (const unsigned short*)conv_w;
    int tid = threadIdx.x;
    float m = 0.f;
    for (int u = tid; u < 36864; u += 256) {
        float v = fabsf(bf2f_raw(cw[u]));
        if (v < 3.0e38f) m = fmaxf(m, v);   // drop inf/NaN patterns
    }
    red[tid] = m;
    __syncthreads();
    for (int s = 128; s > 0; s >>= 1) {
        if (tid < s) red[tid] = fmaxf(red[tid], red[tid + s]);
        __syncthreads();
    }
    if (tid == 0) ws[OFF_FLAG] = (red[0] > 1.0e4f) ? 1.f : 0.f;
}

// ---------------------------------------------------------------------------
// KC: convert/transpose all small weights into fp32 ws slots (dual dtype).
// grid 144 x 256
// ---------------------------------------------------------------------------
__device__ __forceinline__ float ld_in(const void* p, int i, bool f32) {
    if (f32) return ((const float*)p)[i];
    return bf2f_raw(((const unsigned short*)p)[i]);
}

__global__ __launch_bounds__(256) void kc_all(
    const void* conv_w, const void* conv_b, const void* W1, const void* a1,
    const void* W2, const void* a2, const void* Wout, const void* aout,
    const void* tconv_w, const void* tconv_b, float* __restrict__ ws)
{
    bool f32 = ws[OFF_FLAG] != 0.f;
    int idx = blockIdx.x * 256 + threadIdx.x;
    if (f32) {
        if (idx < 36864) {
            int tap = idx >> 12, ic = (idx >> 6) & 63, oc = idx & 63;
            ws[OFF_WC2 + idx] = ((const float*)conv_w)[(oc * 64 + ic) * 9 + tap];
            ws[OFF_WT2 + idx] = ((const float*)tconv_w)[(ic * 64 + oc) * 9 + tap];
        }
        if (idx < 4096) {
            ws[OFF_W1F + idx] = ((const float*)W1)[idx];
            ws[OFF_W2F + idx] = ((const float*)W2)[idx];
        }
        if (idx < 8192) ws[OFF_WOUTF + idx] = ((const float*)Wout)[idx];
        if (idx < 128) {
            ws[OFF_A1F + idx]   = ((const float*)a1)[idx];
            ws[OFF_A2F + idx]   = ((const float*)a2)[idx];
            ws[OFF_AOUTF + idx] = ((const float*)aout)[idx];
        }
        if (idx < 64) {
            ws[OFF_CBF + idx] = ((const float*)conv_b)[idx];
            ws[OFF_TBF + idx] = ((const float*)tconv_b)[idx];
        }
    } else {
        const unsigned short* cw = (const unsigned short*)conv_w;
        const unsigned short* tw = (const unsigned short*)tconv_w;
        if (idx < 36864) {
            int tap = idx >> 12, ic = (idx >> 6) & 63, oc = idx & 63;
            ws[OFF_WC2 + idx] = bf2f_raw(cw[(oc * 64 + ic) * 9 + tap]);
            ws[OFF_WT2 + idx] = bf2f_raw(tw[(ic * 64 + oc) * 9 + tap]);
        }
        if (idx < 4096) {
            ws[OFF_W1F + idx] = bf2f_raw(((const unsigned short*)W1)[idx]);
            ws[OFF_W2F + idx] = bf2f_raw(((const unsigned short*)W2)[idx]);
        }
        if (idx < 8192) ws[OFF_WOUTF + idx] = bf2f_raw(((const unsigned short*)Wout)[idx]);
        if (idx < 128) {
            ws[OFF_A1F + idx]   = bf2f_raw(((const unsigned short*)a1)[idx]);
            ws[OFF_A2F + idx]   = bf2f_raw(((const unsigned short*)a2)[idx]);
            ws[OFF_AOUTF + idx] = bf2f_raw(((const unsigned short*)aout)[idx]);
        }
        if (idx < 64) {
            ws[OFF_CBF + idx] = bf2f_raw(((const unsigned short*)conv_b)[idx]);
            ws[OFF_TBF + idx] = bf2f_raw(((const unsigned short*)tconv_b)[idx]);
        }
    }
}

// ---------------------------------------------------------------------------
// KX: x -> fp32 staging (dual dtype).  grid 4608 x 256 over 1,179,648 elems.
// ---------------------------------------------------------------------------
__global__ __launch_bounds__(256) void kc_x(const void* __restrict__ x,
                                            float* __restrict__ ws)
{
    bool f32 = ws[OFF_FLAG] != 0.f;
    int i = blockIdx.x * 256 + threadIdx.x;   // < 1179648 exactly
    float* xf = ws + OFF_XF32;
    if (f32) xf[i] = ((const float*)x)[i];
    else     xf[i] = bf2f_raw(((const unsigned short*)x)[i]);
}

// ---------------------------------------------------------------------------
// K1: 3x3 stride-2 conv pad 1, direct global reads from XF32.
// grid (9, 8 oc-groups, B) x 256; lanes = flattened n; 8 oc in regs.
// Writes featT[b][oc][n] to BUF0 with a NaN/inf->0 guard (no-op when healthy).
// ---------------------------------------------------------------------------
__global__ __launch_bounds__(256) void k1_conv(float* __restrict__ ws)
{
    int n   = blockIdx.x * 256 + threadIdx.x;   // 0..2303
    int ocb = blockIdx.y * 8;
    int b   = blockIdx.z;
    int oy = n / 48, ox = n - (n / 48) * 48;

    const float* xf = ws + OFF_XF32 + (size_t)b * 64 * 96 * 96;
    const float* wc2 = ws + OFF_WC2;
    float acc[8] = {0, 0, 0, 0, 0, 0, 0, 0};

    for (int ky = 0; ky < 3; ++ky) {
        int iy = 2 * oy - 1 + ky;
        bool vy = (unsigned)iy < 96u;
        int iyc = vy ? iy : 0;
        for (int kx = 0; kx < 3; ++kx) {
            int ix = 2 * ox - 1 + kx;
            bool v = vy && ((unsigned)ix < 96u);
            int ixc = v ? ix : 0;
            const float* xp = xf + iyc * 96 + ixc;           // + ic*9216
            const float* wb = wc2 + (ky * 3 + kx) * 4096 + ocb;
            #pragma unroll 4
            for (int ic = 0; ic < 64; ++ic) {
                float xv = xp[ic * 9216];
                xv = v ? xv : 0.f;
                const float* wr = wb + ic * 64;              // uniform
                #pragma unroll
                for (int o = 0; o < 8; ++o) acc[o] += xv * wr[o];
            }
        }
    }
    float* featT = ws + OFF_BUF0 + (size_t)b * 64 * N_;
    const float* cb = ws + OFF_CBF;
    #pragma unroll
    for (int o = 0; o < 8; ++o) {
        float f = acc[o] + cb[ocb + o];
        f = (fabsf(f) < 1.0e30f) ? f : 0.f;   // NaN/inf guard (bisection aid)
        featT[(ocb + o) * N_ + n] = f;
    }
}

// ---------------------------------------------------------------------------
// K_sq: sq[b][n] = sum_c featT^2.  grid 18 x 256
// ---------------------------------------------------------------------------
__global__ __launch_bounds__(256) void k_sq(float* __restrict__ ws)
{
    int i = blockIdx.x * 256 + threadIdx.x;
    int b = i / N_, n = i - b * N_;
    const float* fT = ws + OFF_BUF0 + (size_t)b * 64 * N_;
    float s = 0.f;
    #pragma unroll 4
    for (int c = 0; c < 64; ++c) { float v = fT[c * N_ + n]; s += v * v; }
    ws[OFF_SQ + i] = s;
}

// ---------------------------------------------------------------------------
// K2: exact top-7 per row, one wave per row.  Lane-local sorted top-7 over its
// 36 j's, then 7-way lexicographic (d2, j) butterfly-min merge across lanes.
// Matches stable double-argsort (rank<=6 == 7 smallest by (value, index)).
// grid 1152 x 256 (4 waves/block)
// ---------------------------------------------------------------------------
__global__ __launch_bounds__(256) void k2_knn(float* __restrict__ ws)
{
    int tid = threadIdx.x;
    int w = tid >> 6, lane = tid & 63;
    int row = blockIdx.x * 4 + w;            // 0..4607
    int b = row / N_, i = row - b * N_;
    const float* fT = ws + OFF_BUF0 + (size_t)b * 64 * N_;
    const float* sq = ws + OFF_SQ + b * N_;
    float sqi = sq[i];

    float lv[7]; int lj[7];
    #pragma unroll
    for (int t = 0; t < 7; ++t) { lv[t] = 3.4e38f; lj[t] = 0x7fffffff; }

    for (int c0 = 0; c0 < 36; ++c0) {
        int j = c0 * 64 + lane;
        float acc = 0.f;
        #pragma unroll 8
        for (int c = 0; c < 64; ++c)
            acc += fT[c * N_ + j] * fT[c * N_ + i];
        float d2 = fmaxf(sqi + sq[j] - 2.f * acc, 0.f);
        if (d2 < lv[6] || (d2 == lv[6] && j < lj[6])) {
            int p = 6;
            while (p > 0 && (lv[p-1] > d2 || (lv[p-1] == d2 && lj[p-1] > j))) {
                lv[p] = lv[p-1]; lj[p] = lj[p-1]; --p;
            }
            lv[p] = d2; lj[p] = j;
        }
    }

    int ptr = 0, myj = 0;
    for (int pass = 0; pass < 7; ++pass) {
        float bv = (ptr < 7) ? lv[ptr] : 3.4e38f;
        int   bj = (ptr < 7) ? lj[ptr] : 0x7fffffff;
        #pragma unroll
        for (int off = 1; off < 64; off <<= 1) {
            float ov = __shfl_xor(bv, off);
            int   oj = __shfl_xor(bj, off);
            if (ov < bv || (ov == bv && oj < bj)) { bv = ov; bj = oj; }
        }
        if (ptr < 7 && lj[ptr] == bj) ++ptr;   // owning lane advances
        if (lane == pass) myj = bj;
    }
    if (lane < 7)
        ((int*)(ws + OFF_KNN))[(size_t)row * 8 + lane] = myj;
}

// ---------------------------------------------------------------------------
// K_lin: outT = inT @ W (64x64); s1/s2 = outT . a halves.  grid 18 x 256
// ---------------------------------------------------------------------------
__global__ __launch_bounds__(256) void k_lin(
    const float* __restrict__ inT, const float* __restrict__ W,
    const float* __restrict__ a, float* __restrict__ outT,
    float* __restrict__ s1, float* __restrict__ s2)
{
    int i = blockIdx.x * 256 + threadIdx.x;
    int b = i / N_, n = i - b * N_;
    const float* in_b = inT + (size_t)b * 64 * N_;
    float acc[64];
    #pragma unroll
    for (int o = 0; o < 64; ++o) acc[o] = 0.f;
    #pragma unroll 2
    for (int k = 0; k < 64; ++k) {
        float xv = in_b[k * N_ + n];
        const float* wr = W + k * 64;
        #pragma unroll
        for (int o = 0; o < 64; ++o) acc[o] += xv * wr[o];
    }
    float* ob = outT + (size_t)b * 64 * N_;
    float p1 = 0.f, p2 = 0.f;
    #pragma unroll
    for (int o = 0; o < 64; ++o) {
        ob[o * N_ + n] = acc[o];
        p1 += acc[o] * a[o];
        p2 += acc[o] * a[64 + o];
    }
    s1[i] = p1;
    s2[i] = p2;
}

// ---------------------------------------------------------------------------
// K_lin2: outT = [h1|h2] @ Wout (128x64).  grid 18 x 256
// ---------------------------------------------------------------------------
__global__ __launch_bounds__(256) void k_lin2(
    const float* __restrict__ h1T, const float* __restrict__ h2T,
    const float* __restrict__ W, const float* __restrict__ a,
    float* __restrict__ outT, float* __restrict__ s1, float* __restrict__ s2)
{
    int i = blockIdx.x * 256 + threadIdx.x;
    int b = i / N_, n = i - b * N_;
    const float* h1 = h1T + (size_t)b * 64 * N_;
    const float* h2 = h2T + (size_t)b * 64 * N_;
    float acc[64];
    #pragma unroll
    for (int o = 0; o < 64; ++o) acc[o] = 0.f;
    #pragma unroll 2
    for (int k = 0; k < 64; ++k) {
        float xv = h1[k * N_ + n];
        const float* wr = W + k * 64;
        #pragma unroll
        for (int o = 0; o < 64; ++o) acc[o] += xv * wr[o];
    }
    #pragma unroll 2
    for (int k = 0; k < 64; ++k) {
        float xv = h2[k * N_ + n];
        const float* wr = W + (64 + k) * 64;
        #pragma unroll
        for (int o = 0; o < 64; ++o) acc[o] += xv * wr[o];
    }
    float* ob = outT + (size_t)b * 64 * N_;
    float p1 = 0.f, p2 = 0.f;
    #pragma unroll
    for (int o = 0; o < 64; ++o) {
        ob[o * N_ + n] = acc[o];
        p1 += acc[o] * a[o];
        p2 += acc[o] * a[64 + o];
    }
    s1[i] = p1;
    s2[i] = p2;
}

// ---------------------------------------------------------------------------
// K_attn: sparse GAT softmax over 7-NN + ELU.  grid 18 x 256
// ---------------------------------------------------------------------------
__global__ __launch_bounds__(256) void k_attn(
    const float* __restrict__ WhT, const float* __restrict__ s1,
    const float* __restrict__ s2, const int* __restrict__ knn,
    float* __restrict__ out)
{
    int i = blockIdx.x * 256 + threadIdx.x;
    int b = i / N_, n = i - b * N_;
    const int* kp = knn + (size_t)i * 8;
    int j[7];
    #pragma unroll
    for (int t = 0; t < 7; ++t) {
        int jt = kp[t];
        j[t] = ((unsigned)jt < (unsigned)N_) ? jt : 0;
    }
    float si = s1[i];
    const float* s2b = s2 + b * N_;
    float e[7];
    #pragma unroll
    for (int t = 0; t < 7; ++t) {
        float v = si + s2b[j[t]];
        e[t] = v > 0.f ? v : 0.2f * v;
    }
    float m = e[0];
    #pragma unroll
    for (int t = 1; t < 7; ++t) m = fmaxf(m, e[t]);
    float ssum = 0.f;
    #pragma unroll
    for (int t = 0; t < 7; ++t) { e[t] = __expf(e[t] - m); ssum += e[t]; }
    float inv = 1.f / ssum;
    #pragma unroll
    for (int t = 0; t < 7; ++t) e[t] *= inv;

    const float* Wb = WhT + (size_t)b * 64 * N_;
    float* ob = out + (size_t)b * 64 * N_;
    #pragma unroll 2
    for (int c = 0; c < 64; ++c) {
        const float* Wc = Wb + c * N_;
        float a = 0.f;
        #pragma unroll
        for (int t = 0; t < 7; ++t) a += e[t] * Wc[j[t]];
        a = a > 0.f ? a : expm1f(a);
        ob[c * N_ + n] = a;
    }
}

// ---------------------------------------------------------------------------
// K7: ConvTranspose2d k=3 s=2 p=1 op=1 : 48x48 -> 96x96, direct global reads.
// grid 288 x 256; 16 oc per thread; dual-dtype output store.
// ---------------------------------------------------------------------------
__global__ __launch_bounds__(256) void k7_tconv(float* __restrict__ ws,
                                                void* __restrict__ outp)
{
    bool f32 = ws[OFF_FLAG] != 0.f;
    int t = blockIdx.x * 256 + threadIdx.x;    // 0..73727
    int pix = t % 9216;
    int g16 = (t / 9216) % 4;
    int b   = t / 36864;
    int oy = pix / 96, ox = pix - (pix / 96) * 96;
    int ocb = g16 * 16;

    const float* gT  = ws + OFF_BUF3 + (size_t)b * 64 * N_;
    const float* wt2 = ws + OFF_WT2;
    float acc[16];
    #pragma unroll
    for (int o = 0; o < 16; ++o) acc[o] = 0.f;

    for (int ky = 0; ky < 3; ++ky) {
        int ty = oy + 1 - ky;
        bool vy = ((ty & 1) == 0) && ((unsigned)(ty >> 1) < 48u);
        int iy = vy ? (ty >> 1) : 0;
        for (int kx = 0; kx < 3; ++kx) {
            int tx = ox + 1 - kx;
            bool v = vy && ((tx & 1) == 0) && ((unsigned)(tx >> 1) < 48u);
            int ix = v ? (tx >> 1) : 0;
            const float* gp = gT + iy * 48 + ix;                 // + ic*N_
            const float* wb = wt2 + (ky * 3 + kx) * 4096 + ocb;  // uniform
            #pragma unroll 4
            for (int ic = 0; ic < 64; ++ic) {
                float gv = gp[ic * N_];
                gv = v ? gv : 0.f;
                const float* wr = wb + ic * 64;
                #pragma unroll
                for (int o = 0; o < 16; ++o) acc[o] += gv * wr[o];
            }
        }
    }
    const float* tb = ws + OFF_TBF;
    size_t base = ((size_t)(b * 64 + ocb) * 96 + oy) * 96 + ox;
    if (f32) {
        float* op = (float*)outp;
        #pragma unroll
        for (int o = 0; o < 16; ++o) op[base + (size_t)o * 9216] = acc[o] + tb[ocb + o];
    } else {
        bf16* op = (bf16*)outp;
        #pragma unroll
        for (int o = 0; o < 16; ++o)
            op[base + (size_t)o * 9216] = __float2bfloat16(acc[o] + tb[ocb + o]);
    }
}

// ---------------------------------------------------------------------------
extern "C" void kernel_launch(void* const* d_in, const int* in_sizes, int n_in,
                              void* d_out, int out_size, void* d_ws, size_t ws_size,
                              hipStream_t stream)
{
    float* ws = (float*)d_ws;
    const int* knn = (const int*)(ws + OFF_KNN);

    hipLaunchKernelGGL(kd_detect, dim3(1), dim3(256), 0, stream, d_in[1], ws);
    hipLaunchKernelGGL(kc_all, dim3(144), dim3(256), 0, stream,
                       d_in[1], d_in[2], d_in[3], d_in[4], d_in[5], d_in[6],
                       d_in[7], d_in[8], d_in[9], d_in[10], ws);
    hipLaunchKernelGGL(kc_x, dim3(4608), dim3(256), 0, stream, d_in[0], ws);
    hipLaunchKernelGGL(k1_conv, dim3(9, 8, 2), dim3(256), 0, stream, ws);
    hipLaunchKernelGGL(k_sq, dim3(18), dim3(256), 0, stream, ws);
    hipLaunchKernelGGL(k2_knn, dim3(1152), dim3(256), 0, stream, ws);
    // layer 1: feat(BUF0) -> Wh1(BUF1) -> h1(BUF2)
    hipLaunchKernelGGL(k_lin, dim3(18), dim3(256), 0, stream,
                       ws + OFF_BUF0, ws + OFF_W1F, ws + OFF_A1F,
                       ws + OFF_BUF1, ws + OFF_S11, ws + OFF_S12);
    hipLaunchKernelGGL(k_attn, dim3(18), dim3(256), 0, stream,
                       ws + OFF_BUF1, ws + OFF_S11, ws + OFF_S12, knn, ws + OFF_BUF2);
    // layer 2: feat(BUF0) -> Wh2(BUF3) -> h2(BUF1)
    hipLaunchKernelGGL(k_lin, dim3(18), dim3(256), 0, stream,
                       ws + OFF_BUF0, ws + OFF_W2F, ws + OFF_A2F,
                       ws + OFF_BUF3, ws + OFF_S21, ws + OFF_S22);
    hipLaunchKernelGGL(k_attn, dim3(18), dim3(256), 0, stream,
                       ws + OFF_BUF3, ws + OFF_S21, ws + OFF_S22, knn, ws + OFF_BUF1);
    // out layer: [h1|h2](BUF2,BUF1) -> Whout(BUF0) -> g(BUF3)
    hipLaunchKernelGGL(k_lin2, dim3(18), dim3(256), 0, stream,
                       ws + OFF_BUF2, ws + OFF_BUF1, ws + OFF_WOUTF, ws + OFF_AOUTF,
                       ws + OFF_BUF0, ws + OFF_S1O, ws + OFF_S2O);
    hipLaunchKernelGGL(k_attn, dim3(18), dim3(256), 0, stream,
                       ws + OFF_BUF0, ws + OFF_S1O, ws + OFF_S2O, knn, ws + OFF_BUF3);
    hipLaunchKernelGGL(k7_tconv, dim3(288), dim3(256), 0, stream, ws, d_out);
}